// Round 7
// baseline (76.852 us; speedup 1.0000x reference)
//
#include <hip/hip_runtime.h>

#define NQ 8
#define KK 4
#define LIN 512
#define LOUT 511            // (512 + 2*1 - 4)/1 + 1
#define BATCH 8
#define NCIRC (BATCH * LOUT)  // 4088
#define NBLOCKS (NCIRC / 8)   // 511 blocks x 8 circuits

// Cross-call state (.bss zero at load; kernel self-resets after each call).
#define ENC0 0xC0000000u      // enc(v) = bits(v) + 0xC0000000, v in [0,1] -> enc > 0 always
__device__ unsigned g_acc[BATCH * NQ];  // encoded running maxima
__device__ unsigned g_cnt;              // finished-block counter

typedef float v2f __attribute__((ext_vector_type(2)));

// ---------------------------------------------------------------------------
// Lane-exchange lane^M.
//  DPP primitives: quad_perm (1,2,3), row_ror:8 (8), row_half_mirror (7), row_mirror (15).
//  Composites (2 DPP): 4=7^3, 5=7^2, 6=7^1, 12=15^3.
//  DS swizzle xor-mode only for masks crossing lane bit 4 (16,24).
template<int CTRL> __device__ __forceinline__ float dpp1(float v) {
    return __builtin_bit_cast(float, __builtin_amdgcn_update_dpp(
        0, __builtin_bit_cast(int, v), CTRL, 0xF, 0xF, true));
}
template<int M> __device__ __forceinline__ float lx(float v) {
    if constexpr (M == 1)       return dpp1<0xB1>(v);           // quad [1,0,3,2]
    else if constexpr (M == 2)  return dpp1<0x4E>(v);           // quad [2,3,0,1]
    else if constexpr (M == 3)  return dpp1<0x1B>(v);           // quad [3,2,1,0]
    else if constexpr (M == 7)  return dpp1<0x141>(v);          // row_half_mirror
    else if constexpr (M == 8)  return dpp1<0x128>(v);          // row_ror:8
    else if constexpr (M == 15) return dpp1<0x140>(v);          // row_mirror
    else if constexpr (M == 4)  return lx<3>(lx<7>(v));
    else if constexpr (M == 5)  return lx<2>(lx<7>(v));
    else if constexpr (M == 6)  return lx<1>(lx<7>(v));
    else if constexpr (M == 12) return lx<3>(lx<15>(v));
    else
        return __builtin_bit_cast(float, __builtin_amdgcn_ds_swizzle(
            __builtin_bit_cast(int, v), (M << 10) | 0x1F));     // xor mode
}

// ===========================================================================
// R=8 packed: 2 circuits/wave, circuit = 32 lanes, amp a = (lane&31)<<3 | r.
// st[r].x = re, st[r].y = im.  Qubits 0..4 -> lane bits 4..0; 5..7 -> reg 2..0.
// ===========================================================================
template<int LB>
__device__ __forceinline__ void rx_lane(v2f (&st)[8], float c, float s) {
    constexpr int M = 1 << LB;
    const v2f c2 = {c, c}, sv = {s, -s};
    #pragma unroll
    for (int r = 0; r < 8; ++r) {
        v2f ov = { lx<M>(st[r].y), lx<M>(st[r].x) };   // (other_im, other_re)
        st[r] = c2 * st[r] + sv * ov;
    }
}

template<int LB>
__device__ __forceinline__ void ry_lane(v2f (&st)[8], float c, float s, int lane) {
    constexpr int M = 1 << LB;
    const float sg = ((lane >> LB) & 1) ? s : -s;
    const v2f c2 = {c, c}, sg2 = {sg, sg};
    #pragma unroll
    for (int r = 0; r < 8; ++r) {
        v2f ov = { lx<M>(st[r].x), lx<M>(st[r].y) };
        st[r] = c2 * st[r] + sg2 * ov;
    }
}

template<int LB>
__device__ __forceinline__ void rz_lane(v2f (&st)[8], float c, float s, int lane) {
    const float t = ((lane >> LB) & 1) ? -s : s;
    const v2f c2 = {c, c}, tv = {t, -t};
    #pragma unroll
    for (int r = 0; r < 8; ++r) {
        v2f sw = { st[r].y, st[r].x };
        st[r] = c2 * st[r] + tv * sw;
    }
}

template<int RB>
__device__ __forceinline__ void rx_reg(v2f (&st)[8], float c, float s) {
    constexpr int m = 1 << RB;
    const v2f c2 = {c, c}, sv = {s, -s};
    #pragma unroll
    for (int r = 0; r < 8; ++r) {
        if ((r & m) == 0) {
            const int a = r, b = r | m;
            v2f A = st[a], B = st[b];
            v2f swA = { A.y, A.x }, swB = { B.y, B.x };
            st[a] = c2 * A + sv * swB;
            st[b] = c2 * B + sv * swA;
        }
    }
}

template<int RB>
__device__ __forceinline__ void ry_reg(v2f (&st)[8], float c, float s) {
    constexpr int m = 1 << RB;
    const v2f c2 = {c, c}, s2 = {s, s};
    #pragma unroll
    for (int r = 0; r < 8; ++r) {
        if ((r & m) == 0) {
            const int a = r, b = r | m;
            v2f A = st[a], B = st[b];
            st[a] = c2 * A - s2 * B;
            st[b] = c2 * B + s2 * A;
        }
    }
}

template<int RB>
__device__ __forceinline__ void rz_reg(v2f (&st)[8], float c, float s) {
    const v2f c2 = {c, c};
    #pragma unroll
    for (int r = 0; r < 8; ++r) {
        const float t = ((r >> RB) & 1) ? -s : s;
        const v2f tv = {t, -t};
        v2f sw = { st[r].y, st[r].x };
        st[r] = c2 * st[r] + tv * sw;
    }
}

// fused CNOT.RY(control).CNOT, control & target both lane bits
template<int LBc, int LBt>
__device__ __forceinline__ void fry_ll(v2f (&st)[8], float c, float s, int lane) {
    constexpr int M = (1 << LBc) | (1 << LBt);
    const float sg = ((lane >> LBc) & 1) ? s : -s;
    const v2f c2 = {c, c}, sg2 = {sg, sg};
    #pragma unroll
    for (int r = 0; r < 8; ++r) {
        v2f ov = { lx<M>(st[r].x), lx<M>(st[r].y) };
        st[r] = c2 * st[r] + sg2 * ov;
    }
}

// control lane bit, target reg bit
template<int LBc, int RBt>
__device__ __forceinline__ void fry_lr(v2f (&st)[8], float c, float s, int lane) {
    constexpr int M = 1 << LBc;
    constexpr int mt = 1 << RBt;
    const float sg = ((lane >> LBc) & 1) ? s : -s;
    const v2f c2 = {c, c}, sg2 = {sg, sg};
    v2f ov[8];
    #pragma unroll
    for (int r = 0; r < 8; ++r)
        ov[r] = v2f{ lx<M>(st[r ^ mt].x), lx<M>(st[r ^ mt].y) };
    #pragma unroll
    for (int r = 0; r < 8; ++r)
        st[r] = c2 * st[r] + sg2 * ov[r];
}

// control & target both reg bits
template<int RBc, int RBt>
__device__ __forceinline__ void fry_rr(v2f (&st)[8], float c, float s) {
    constexpr int mm = (1 << RBc) | (1 << RBt);
    const v2f c2 = {c, c};
    v2f nv[8];
    #pragma unroll
    for (int r = 0; r < 8; ++r) {
        const float sg = ((r >> RBc) & 1) ? s : -s;
        const v2f sg2 = {sg, sg};
        nv[r] = c2 * st[r] + sg2 * st[r ^ mm];
    }
    #pragma unroll
    for (int r = 0; r < 8; ++r) st[r] = nv[r];
}

// j=7: q0(lane bit 4)-conditional RY on q7 (reg bit 0) — no exchange
__device__ __forceinline__ void cry_q7(v2f (&st)[8], float c, float s, int lane) {
    const float se = ((lane >> 4) & 1) ? -s : s;
    const v2f c2 = {c, c}, se2 = {se, se};
    #pragma unroll
    for (int p = 0; p < 4; ++p) {
        const int a = 2*p, b = 2*p + 1;
        v2f A = st[a], B = st[b];
        st[a] = c2 * A - se2 * B;
        st[b] = c2 * B + se2 * A;
    }
}

// Full ansatz; t[j*3 + {0:rx,1:fry,2:rz}] = (cos,sin) pairs (VGPR-resident).
// last=true: drop all RZ (diagonal, commutes to Z-measurement — exact).
__device__ __forceinline__ void ansatz8(v2f (&st)[8], const v2f (&t)[24], int lane, bool last) {
    rx_lane<4>(st, t[0].x, t[0].y);                    // M=16 DS
    fry_ll<4,3>(st, t[1].x, t[1].y, lane);             // M=24 DS
    if (!last) rz_lane<4>(st, t[2].x, t[2].y, lane);
    rx_lane<3>(st, t[3].x, t[3].y);                    // M=8 DPP
    fry_ll<3,2>(st, t[4].x, t[4].y, lane);             // M=12 -> 2xDPP
    if (!last) rz_lane<3>(st, t[5].x, t[5].y, lane);
    rx_lane<2>(st, t[6].x, t[6].y);                    // M=4 -> 2xDPP
    fry_ll<2,1>(st, t[7].x, t[7].y, lane);             // M=6 -> 2xDPP
    if (!last) rz_lane<2>(st, t[8].x, t[8].y, lane);
    rx_lane<1>(st, t[9].x, t[9].y);                    // M=2 DPP
    fry_ll<1,0>(st, t[10].x, t[10].y, lane);           // M=3 DPP
    if (!last) rz_lane<1>(st, t[11].x, t[11].y, lane);
    rx_lane<0>(st, t[12].x, t[12].y);                  // M=1 DPP
    fry_lr<0,2>(st, t[13].x, t[13].y, lane);           // M=1 DPP
    if (!last) rz_lane<0>(st, t[14].x, t[14].y, lane);
    rx_reg<2>(st, t[15].x, t[15].y);
    fry_rr<2,1>(st, t[16].x, t[16].y);
    if (!last) rz_reg<2>(st, t[17].x, t[17].y);
    rx_reg<1>(st, t[18].x, t[18].y);
    fry_rr<1,0>(st, t[19].x, t[19].y);
    if (!last) rz_reg<1>(st, t[20].x, t[20].y);
    rx_reg<0>(st, t[21].x, t[21].y);
    cry_q7(st, t[22].x, t[22].y, lane);
    if (!last) rz_reg<0>(st, t[23].x, t[23].y);
}

// Data re-upload: RY(x_k) on qubits k and k+4
__device__ __forceinline__ void reup8(v2f (&st)[8],
                                      const float (&xc)[4], const float (&xs)[4], int lane) {
    ry_lane<4>(st, xc[0], xs[0], lane);  ry_lane<0>(st, xc[0], xs[0], lane);  // q0, q4
    ry_lane<3>(st, xc[1], xs[1], lane);  ry_reg<2>(st, xc[1], xs[1]);          // q1, q5
    ry_lane<2>(st, xc[2], xs[2], lane);  ry_reg<1>(st, xc[2], xs[2]);          // q2, q6
    ry_lane<1>(st, xc[3], xs[3], lane);  ry_reg<0>(st, xc[3], xs[3]);          // q3, q7
}

// Signed butterfly over 5 lane bits; qubit q (0..4) gets its sign at stage 4-q.
template<int ST>
__device__ __forceinline__ void bstage8(float (&z)[8], int lane) {
    constexpr int M = 1 << ST;
    #pragma unroll
    for (int q = 0; q < 8; ++q) {
        float o = lx<M>(z[q]);
        if (q < 5 && (4 - q) == ST)
            z[q] = ((lane >> ST) & 1) ? (o - z[q]) : (z[q] - o);
        else
            z[q] += o;
    }
}

// ---------------------------------------------------------------------------
__global__ __launch_bounds__(256) void quanv_kernel(const float* __restrict__ vec,
                                                    const float* __restrict__ wts,
                                                    float* __restrict__ out) {
    __shared__ v2f tt2[120];        // (cos, sin) of 0.5*w for all 120 weight angles
    const int tid = threadIdx.x;
    if (tid < 120) {
        float a = 0.5f * wts[tid];
        float s, c;
        __sincosf(a, &s, &c);
        tt2[tid] = v2f{c, s};
    }

    const int lane = tid & 63;                      // only low 5 bits used for gates
    const int pos = tid & 31;                       // lane within circuit
    const int circ = blockIdx.x * 8 + (tid >> 5);   // 511 blocks * 8 = 4088 exact
    const int b = circ / LOUT;
    const int op = circ - b * LOUT;

    // patch trig (shared by all 4 re-upload layers)
    float xc[4], xs[4];
    #pragma unroll
    for (int k = 0; k < KK; ++k) {
        int idx = op - 1 + k;
        int ic = idx < 0 ? 0 : (idx > LIN - 1 ? LIN - 1 : idx);
        float xv = vec[b * LIN + ic];
        xv = (idx == ic) ? xv : 0.0f;
        float a = 0.5f * xv;
        xs[k] = __sinf(a); xc[k] = __cosf(a);
    }

    // |0..0>  (amp 0 lives in pos 0, reg 0 of each circuit half)
    v2f st[8];
    #pragma unroll
    for (int r = 0; r < 8; ++r) st[r] = v2f{0.f, 0.f};
    if (pos == 0) st[0] = v2f{1.f, 0.f};

    __syncthreads();                                // trig table ready

    #pragma unroll 1
    for (int L = 0; L <= 4; ++L) {                  // rolled: keep body in I$
        v2f tab[24];
        #pragma unroll
        for (int i = 0; i < 24; ++i) tab[i] = tt2[L * 24 + i];
        if (L) reup8(st, xc, xs, lane);
        ansatz8(st, tab, lane, L == 4);             // final layer: RZs dropped (exact)
    }

    // per-lane signed partials: reg qubits 5,6,7 <-> r bits 2,1,0
    float p[8];
    #pragma unroll
    for (int r = 0; r < 8; ++r) p[r] = st[r].x*st[r].x + st[r].y*st[r].y;
    float pl = 0.f, z5 = 0.f, z6 = 0.f, z7 = 0.f;
    #pragma unroll
    for (int r = 0; r < 8; ++r) {
        pl += p[r];
        z5 += ((r >> 2) & 1) ? -p[r] : p[r];
        z6 += ((r >> 1) & 1) ? -p[r] : p[r];
        z7 += ( r       & 1) ? -p[r] : p[r];
    }
    float z[8];
    z[0] = pl; z[1] = pl; z[2] = pl; z[3] = pl; z[4] = pl;  // signs in butterfly
    z[5] = z5; z[6] = z6; z[7] = z7;

    bstage8<0>(z, lane); bstage8<1>(z, lane); bstage8<2>(z, lane);
    bstage8<3>(z, lane); bstage8<4>(z, lane);

    // block reduction over 8 circuits, then encoded atomicMax into g_acc
    __shared__ float zsh[8][NQ];
    __shared__ int bsh[8];
    __shared__ int lastFlag;
    const int g = tid >> 5;
    if (pos == 0) {
        bsh[g] = b;
        #pragma unroll
        for (int q = 0; q < NQ; ++q) zsh[g][q] = fmaxf(z[q], 0.0f);
    }
    __syncthreads();
    if (tid < 64) {
        const int gg = tid >> 3, q = tid & 7;
        const bool leader = (gg == 0) || (bsh[gg] != bsh[gg - 1]);
        if (leader) {
            float m = zsh[gg][q];
            for (int g2 = gg + 1; g2 < 8 && bsh[g2] == bsh[gg]; ++g2)
                m = fmaxf(m, zsh[g2][q]);
            atomicMax(&g_acc[bsh[gg] * NQ + q], __float_as_uint(m) + ENC0);
        }
    }
    __syncthreads();

    // last block decodes to d_out and resets state for the next call
    if (tid == 0) {
        __threadfence();
        unsigned old = atomicAdd(&g_cnt, 1u);
        lastFlag = (old == NBLOCKS - 1);
    }
    __syncthreads();
    if (lastFlag && tid < BATCH * NQ) {
        unsigned e = atomicMax(&g_acc[tid], 0u);    // atomic read of final max
        out[tid] = __uint_as_float(e - ENC0);
        g_acc[tid] = ENC0;                          // reset (all writers done)
        if (tid == 0) g_cnt = 0u;
    }
}

extern "C" void kernel_launch(void* const* d_in, const int* in_sizes, int n_in,
                              void* d_out, int out_size, void* d_ws, size_t ws_size,
                              hipStream_t stream) {
    const float* vec = (const float*)d_in[0];   // (8,1,512) float32
    const float* wts = (const float*)d_in[1];   // (5,8,3) float32
    float* out = (float*)d_out;                 // (8,8,1) float32

    hipLaunchKernelGGL(quanv_kernel, dim3(NBLOCKS), dim3(256), 0, stream, vec, wts, out);
}

// Round 8
// 72.446 us; speedup vs baseline: 1.0608x; 1.0608x over previous
//
#include <hip/hip_runtime.h>

#define NQ 8
#define KK 4
#define LIN 512
#define LOUT 511            // (512 + 2*1 - 4)/1 + 1
#define BATCH 8
#define NCIRC (BATCH * LOUT)  // 4088

// Cross-kernel scratch, rewritten by prep_kernel every launch.
__device__ float g_tab[240];   // (cos, sin) of 0.5*w for all 120 weight angles
__device__ float g_st0[512];   // state after ansatz layer 0 on |0..0>, (re,im) per flat amp

typedef float v2f __attribute__((ext_vector_type(2)));

// ---------------------------------------------------------------------------
// Lane-exchange lane^M.
//  DPP primitives: quad_perm (masks 1,2,3), row_ror:8 (mask 8),
//  row_half_mirror (mask 7), row_mirror (mask 15).
//  Composites (2 DPP, pure VALU): 4=7^3, 5=7^2, 6=7^1, 12=15^3.
//  DS swizzle xor-mode only for masks crossing lane bit 4 (16,24).
template<int CTRL> __device__ __forceinline__ float dpp1(float v) {
    return __builtin_bit_cast(float, __builtin_amdgcn_update_dpp(
        0, __builtin_bit_cast(int, v), CTRL, 0xF, 0xF, true));
}
template<int M> __device__ __forceinline__ float lx(float v) {
    if constexpr (M == 1)       return dpp1<0xB1>(v);           // quad [1,0,3,2]
    else if constexpr (M == 2)  return dpp1<0x4E>(v);           // quad [2,3,0,1]
    else if constexpr (M == 3)  return dpp1<0x1B>(v);           // quad [3,2,1,0]
    else if constexpr (M == 7)  return dpp1<0x141>(v);          // row_half_mirror
    else if constexpr (M == 8)  return dpp1<0x128>(v);          // row_ror:8
    else if constexpr (M == 15) return dpp1<0x140>(v);          // row_mirror
    else if constexpr (M == 4)  return lx<3>(lx<7>(v));
    else if constexpr (M == 5)  return lx<2>(lx<7>(v));
    else if constexpr (M == 6)  return lx<1>(lx<7>(v));
    else if constexpr (M == 12) return lx<3>(lx<15>(v));
    else if constexpr (M < 32)
        return __builtin_bit_cast(float, __builtin_amdgcn_ds_swizzle(
            __builtin_bit_cast(int, v), (M << 10) | 0x1F));     // xor mode
    else
        return __shfl_xor(v, M, 64);
}

// ===========================================================================
// R=4 gate set (amp = lane*4 + r) — prep_kernel's layer-0 evolve only.
// ===========================================================================
template<int BP>
__device__ __forceinline__ void g_rx4(float (&sr)[4], float (&si)[4], float c, float s, int lane) {
    if constexpr (BP >= 2) {
        constexpr int M = 1 << (BP - 2);
        #pragma unroll
        for (int r = 0; r < 4; ++r) {
            float orr = lx<M>(sr[r]), oii = lx<M>(si[r]);
            float nr = c * sr[r] + s * oii;
            float ni = c * si[r] - s * orr;
            sr[r] = nr; si[r] = ni;
        }
    } else if constexpr (BP == 1) {
        #pragma unroll
        for (int p = 0; p < 2; ++p) {
            const int a = p, b = p + 2;
            float ar = sr[a], ai = si[a], br = sr[b], bi = si[b];
            sr[a] = c*ar + s*bi;  si[a] = c*ai - s*br;
            sr[b] = c*br + s*ai;  si[b] = c*bi - s*ar;
        }
    } else {
        #pragma unroll
        for (int p = 0; p < 2; ++p) {
            const int a = 2*p, b = 2*p + 1;
            float ar = sr[a], ai = si[a], br = sr[b], bi = si[b];
            sr[a] = c*ar + s*bi;  si[a] = c*ai - s*br;
            sr[b] = c*br + s*ai;  si[b] = c*bi - s*ar;
        }
    }
}

template<int BP>
__device__ __forceinline__ void g_rz4(float (&sr)[4], float (&si)[4], float c, float s, int lane) {
    if constexpr (BP >= 2) {
        const float t = ((lane >> (BP - 2)) & 1) ? -s : s;
        #pragma unroll
        for (int r = 0; r < 4; ++r) {
            float nr = c * sr[r] + t * si[r];
            float ni = c * si[r] - t * sr[r];
            sr[r] = nr; si[r] = ni;
        }
    } else if constexpr (BP == 1) {
        #pragma unroll
        for (int r = 0; r < 4; ++r) {
            const float t = (r < 2) ? s : -s;
            float nr = c * sr[r] + t * si[r];
            float ni = c * si[r] - t * sr[r];
            sr[r] = nr; si[r] = ni;
        }
    } else {
        #pragma unroll
        for (int r = 0; r < 4; ++r) {
            const float t = ((r & 1) == 0) ? s : -s;
            float nr = c * sr[r] + t * si[r];
            float ni = c * si[r] - t * sr[r];
            sr[r] = nr; si[r] = ni;
        }
    }
}

// Fused CNOT.RY(control).CNOT (j=0..6)
template<int BPC, int BPT>
__device__ __forceinline__ void g_fry4(float (&sr)[4], float (&si)[4], float c, float s, int lane) {
    if constexpr (BPT >= 2) {
        constexpr int M = (1 << (BPC - 2)) | (1 << (BPT - 2));
        const float sg = ((lane >> (BPC - 2)) & 1) ? s : -s;
        #pragma unroll
        for (int r = 0; r < 4; ++r) {
            float orr = lx<M>(sr[r]), oii = lx<M>(si[r]);
            sr[r] = c * sr[r] + sg * orr;
            si[r] = c * si[r] + sg * oii;
        }
    } else if constexpr (BPT == 1) {
        constexpr int M = 1 << (BPC - 2);
        const float sg = ((lane >> (BPC - 2)) & 1) ? s : -s;
        float pr[4], pi[4];
        #pragma unroll
        for (int r = 0; r < 4; ++r) { pr[r] = lx<M>(sr[r ^ 2]); pi[r] = lx<M>(si[r ^ 2]); }
        #pragma unroll
        for (int r = 0; r < 4; ++r) { sr[r] = c*sr[r] + sg*pr[r]; si[r] = c*si[r] + sg*pi[r]; }
    } else if constexpr (BPC == 1) {
        float t0r = sr[0], t0i = si[0], t1r = sr[1], t1i = si[1];
        sr[0] = c*sr[0] - s*sr[3];  si[0] = c*si[0] - s*si[3];
        sr[1] = c*sr[1] - s*sr[2];  si[1] = c*si[1] - s*si[2];
        sr[2] = c*sr[2] + s*t1r;    si[2] = c*si[2] + s*t1i;
        sr[3] = c*sr[3] + s*t0r;    si[3] = c*si[3] + s*t0i;
    } else {
        constexpr int M = 1 << (BPC - 2);
        const float sg = ((lane >> (BPC - 2)) & 1) ? s : -s;
        float pr[4], pi[4];
        #pragma unroll
        for (int r = 0; r < 4; ++r) { pr[r] = lx<M>(sr[r ^ 1]); pi[r] = lx<M>(si[r ^ 1]); }
        #pragma unroll
        for (int r = 0; r < 4; ++r) { sr[r] = c*sr[r] + sg*pr[r]; si[r] = c*si[r] + sg*pi[r]; }
    }
}

// j=7: RY on TARGET (q7) of CNOT(0,7) -> q0-conditional RY, no exchange.
__device__ __forceinline__ void g_cry4_q7(float (&sr)[4], float (&si)[4], float c, float s, int lane) {
    const float se = ((lane >> 5) & 1) ? -s : s;
    #pragma unroll
    for (int p = 0; p < 2; ++p) {
        const int a = 2*p, b = 2*p + 1;
        float ar = sr[a], ai = si[a], br = sr[b], bi = si[b];
        sr[a] = c*ar - se*br;  si[a] = c*ai - se*bi;
        sr[b] = se*ar + c*br;  si[b] = se*ai + c*bi;
    }
}

template<int J>
__device__ __forceinline__ void astep4(float (&sr)[4], float (&si)[4],
                                       const float* __restrict__ t48, int lane) {
    constexpr int BP = 7 - J;
    g_rx4<BP>(sr, si, t48[J*6 + 0], t48[J*6 + 1], lane);
    if constexpr (J < 7) {
        g_fry4<7 - J, 6 - J>(sr, si, t48[J*6 + 2], t48[J*6 + 3], lane);
    } else {
        g_cry4_q7(sr, si, t48[J*6 + 2], t48[J*6 + 3], lane);
    }
    g_rz4<BP>(sr, si, t48[J*6 + 4], t48[J*6 + 5], lane);
}

// ===========================================================================
// R=8, packed: 2 circuits/wave, circuit = 32 lanes, amp a = (lane&31)<<3 | r.
// State: v2f st[8], st[r].x = re, st[r].y = im.  (float2 math -> v_pk_fma_f32)
// Qubits 0..4 -> lane bits 4..0; qubits 5..7 -> reg bits 2..0.
// ===========================================================================
template<int LB>
__device__ __forceinline__ void rx_lane(v2f (&st)[8], float c, float s) {
    constexpr int M = 1 << LB;
    const v2f c2 = {c, c}, sv = {s, -s};
    #pragma unroll
    for (int r = 0; r < 8; ++r) {
        v2f ov = { lx<M>(st[r].y), lx<M>(st[r].x) };   // (other_im, other_re)
        st[r] = c2 * st[r] + sv * ov;
    }
}

template<int LB>
__device__ __forceinline__ void ry_lane(v2f (&st)[8], float c, float s, int lane) {
    constexpr int M = 1 << LB;
    const float sg = ((lane >> LB) & 1) ? s : -s;
    const v2f c2 = {c, c}, sg2 = {sg, sg};
    #pragma unroll
    for (int r = 0; r < 8; ++r) {
        v2f ov = { lx<M>(st[r].x), lx<M>(st[r].y) };
        st[r] = c2 * st[r] + sg2 * ov;
    }
}

template<int LB>
__device__ __forceinline__ void rz_lane(v2f (&st)[8], float c, float s, int lane) {
    const float t = ((lane >> LB) & 1) ? -s : s;
    const v2f c2 = {c, c}, tv = {t, -t};
    #pragma unroll
    for (int r = 0; r < 8; ++r) {
        v2f sw = { st[r].y, st[r].x };
        st[r] = c2 * st[r] + tv * sw;
    }
}

template<int RB>
__device__ __forceinline__ void rx_reg(v2f (&st)[8], float c, float s) {
    constexpr int m = 1 << RB;
    const v2f c2 = {c, c}, sv = {s, -s};
    #pragma unroll
    for (int r = 0; r < 8; ++r) {
        if ((r & m) == 0) {
            const int a = r, b = r | m;
            v2f A = st[a], B = st[b];
            v2f swA = { A.y, A.x }, swB = { B.y, B.x };
            st[a] = c2 * A + sv * swB;
            st[b] = c2 * B + sv * swA;
        }
    }
}

template<int RB>
__device__ __forceinline__ void ry_reg(v2f (&st)[8], float c, float s) {
    constexpr int m = 1 << RB;
    const v2f c2 = {c, c}, s2 = {s, s};
    #pragma unroll
    for (int r = 0; r < 8; ++r) {
        if ((r & m) == 0) {
            const int a = r, b = r | m;
            v2f A = st[a], B = st[b];
            st[a] = c2 * A - s2 * B;
            st[b] = c2 * B + s2 * A;
        }
    }
}

template<int RB>
__device__ __forceinline__ void rz_reg(v2f (&st)[8], float c, float s) {
    const v2f c2 = {c, c};
    #pragma unroll
    for (int r = 0; r < 8; ++r) {
        const float t = ((r >> RB) & 1) ? -s : s;
        const v2f tv = {t, -t};
        v2f sw = { st[r].y, st[r].x };
        st[r] = c2 * st[r] + tv * sw;
    }
}

// fused CNOT.RY(control).CNOT, control & target both lane bits
template<int LBc, int LBt>
__device__ __forceinline__ void fry_ll(v2f (&st)[8], float c, float s, int lane) {
    constexpr int M = (1 << LBc) | (1 << LBt);
    const float sg = ((lane >> LBc) & 1) ? s : -s;
    const v2f c2 = {c, c}, sg2 = {sg, sg};
    #pragma unroll
    for (int r = 0; r < 8; ++r) {
        v2f ov = { lx<M>(st[r].x), lx<M>(st[r].y) };
        st[r] = c2 * st[r] + sg2 * ov;
    }
}

// control lane bit, target reg bit
template<int LBc, int RBt>
__device__ __forceinline__ void fry_lr(v2f (&st)[8], float c, float s, int lane) {
    constexpr int M = 1 << LBc;
    constexpr int mt = 1 << RBt;
    const float sg = ((lane >> LBc) & 1) ? s : -s;
    const v2f c2 = {c, c}, sg2 = {sg, sg};
    v2f ov[8];
    #pragma unroll
    for (int r = 0; r < 8; ++r)
        ov[r] = v2f{ lx<M>(st[r ^ mt].x), lx<M>(st[r ^ mt].y) };
    #pragma unroll
    for (int r = 0; r < 8; ++r)
        st[r] = c2 * st[r] + sg2 * ov[r];
}

// control & target both reg bits
template<int RBc, int RBt>
__device__ __forceinline__ void fry_rr(v2f (&st)[8], float c, float s) {
    constexpr int mm = (1 << RBc) | (1 << RBt);
    const v2f c2 = {c, c};
    v2f nv[8];
    #pragma unroll
    for (int r = 0; r < 8; ++r) {
        const float sg = ((r >> RBc) & 1) ? s : -s;
        const v2f sg2 = {sg, sg};
        nv[r] = c2 * st[r] + sg2 * st[r ^ mm];
    }
    #pragma unroll
    for (int r = 0; r < 8; ++r) st[r] = nv[r];
}

// j=7: q0(lane bit 4)-conditional RY on q7 (reg bit 0) — no exchange
__device__ __forceinline__ void cry_q7(v2f (&st)[8], float c, float s, int lane) {
    const float se = ((lane >> 4) & 1) ? -s : s;
    const v2f c2 = {c, c}, se2 = {se, se};
    #pragma unroll
    for (int p = 0; p < 4; ++p) {
        const int a = 2*p, b = 2*p + 1;
        v2f A = st[a], B = st[b];
        st[a] = c2 * A - se2 * B;
        st[b] = c2 * B + se2 * A;
    }
}

// Full ansatz, trig from table t[48] (wave-uniform global -> scalar loads).
// LAST: drop all RZ (exact).
template<bool LAST>
__device__ __forceinline__ void ansatz8(v2f (&st)[8], const float* __restrict__ t, int lane) {
    rx_lane<4>(st, t[0], t[1]);                    // M=16 DS
    fry_ll<4,3>(st, t[2], t[3], lane);             // M=24 DS
    if (!LAST) rz_lane<4>(st, t[4], t[5], lane);
    rx_lane<3>(st, t[6], t[7]);                    // M=8 DPP
    fry_ll<3,2>(st, t[8], t[9], lane);             // M=12 -> 2xDPP
    if (!LAST) rz_lane<3>(st, t[10], t[11], lane);
    rx_lane<2>(st, t[12], t[13]);                  // M=4 -> 2xDPP
    fry_ll<2,1>(st, t[14], t[15], lane);           // M=6 -> 2xDPP
    if (!LAST) rz_lane<2>(st, t[16], t[17], lane);
    rx_lane<1>(st, t[18], t[19]);                  // M=2 DPP
    fry_ll<1,0>(st, t[20], t[21], lane);           // M=3 DPP
    if (!LAST) rz_lane<1>(st, t[22], t[23], lane);
    rx_lane<0>(st, t[24], t[25]);                  // M=1 DPP
    fry_lr<0,2>(st, t[26], t[27], lane);           // M=1 DPP
    if (!LAST) rz_lane<0>(st, t[28], t[29], lane);
    rx_reg<2>(st, t[30], t[31]);
    fry_rr<2,1>(st, t[32], t[33]);
    if (!LAST) rz_reg<2>(st, t[34], t[35]);
    rx_reg<1>(st, t[36], t[37]);
    fry_rr<1,0>(st, t[38], t[39]);
    if (!LAST) rz_reg<1>(st, t[40], t[41]);
    rx_reg<0>(st, t[42], t[43]);
    cry_q7(st, t[44], t[45], lane);
    if (!LAST) rz_reg<0>(st, t[46], t[47]);
}

// Data re-upload: RY(x_k) on qubits k and k+4
__device__ __forceinline__ void reup8(v2f (&st)[8],
                                      const float (&xc)[4], const float (&xs)[4], int lane) {
    ry_lane<4>(st, xc[0], xs[0], lane);  ry_lane<0>(st, xc[0], xs[0], lane);  // q0, q4
    ry_lane<3>(st, xc[1], xs[1], lane);  ry_reg<2>(st, xc[1], xs[1]);          // q1, q5
    ry_lane<2>(st, xc[2], xs[2], lane);  ry_reg<1>(st, xc[2], xs[2]);          // q2, q6
    ry_lane<1>(st, xc[3], xs[3], lane);  ry_reg<0>(st, xc[3], xs[3]);          // q3, q7
}

// Signed butterfly over 5 lane bits; qubit q (0..4) gets its sign at stage 4-q.
template<int ST>
__device__ __forceinline__ void bstage8(float (&z)[8], int lane) {
    constexpr int M = 1 << ST;
    #pragma unroll
    for (int q = 0; q < 8; ++q) {
        float o = lx<M>(z[q]);
        if (q < 5 && (4 - q) == ST)
            z[q] = ((lane >> ST) & 1) ? (o - z[q]) : (z[q] - o);
        else
            z[q] += o;
    }
}

// ---------------------------------------------------------------------------
// Prep: zero out, trig table (global + LDS), layer-0 state via R=4 evolve.
__global__ __launch_bounds__(256) void prep_kernel(const float* __restrict__ wts,
                                                   float* __restrict__ out) {
    __shared__ float tt[240];
    const int t = threadIdx.x;
    if (t < 120) {
        float a = 0.5f * wts[t];
        float cv = __cosf(a), sv = __sinf(a);
        g_tab[2*t] = cv;  g_tab[2*t + 1] = sv;
        tt[2*t] = cv;     tt[2*t + 1] = sv;
    }
    if (t >= 192 && t < 192 + BATCH * NQ) out[t - 192] = 0.0f;
    __syncthreads();
    if (t < 64) {
        const int lane = t;
        float sr[4] = {0.f, 0.f, 0.f, 0.f};
        float si[4] = {0.f, 0.f, 0.f, 0.f};
        if (lane == 0) sr[0] = 1.0f;
        astep4<0>(sr, si, tt, lane); astep4<1>(sr, si, tt, lane);
        astep4<2>(sr, si, tt, lane); astep4<3>(sr, si, tt, lane);
        astep4<4>(sr, si, tt, lane); astep4<5>(sr, si, tt, lane);
        astep4<6>(sr, si, tt, lane); astep4<7>(sr, si, tt, lane);
        float4* st4 = (float4*)g_st0;
        st4[lane*2]     = make_float4(sr[0], si[0], sr[1], si[1]);
        st4[lane*2 + 1] = make_float4(sr[2], si[2], sr[3], si[3]);
    }
}

// ---------------------------------------------------------------------------
__global__ __launch_bounds__(256) void quanv_kernel(const float* __restrict__ vec,
                                                    float* __restrict__ out) {
    const int tid = threadIdx.x;
    const int lane = tid & 63;                // only low 5 bits used for gates
    const int pos = tid & 31;                 // lane within circuit
    const int circ = blockIdx.x * 8 + (tid >> 5);   // 511 blocks * 8 = 4088 exact
    const int b = circ / LOUT;
    const int op = circ - b * LOUT;

    // patch trig (shared by all 4 re-upload layers)
    float xc[4], xs[4];
    #pragma unroll
    for (int k = 0; k < KK; ++k) {
        int idx = op - 1 + k;
        int ic = idx < 0 ? 0 : (idx > LIN - 1 ? LIN - 1 : idx);
        float xv = vec[b * LIN + ic];
        xv = (idx == ic) ? xv : 0.0f;
        float a = 0.5f * xv;
        xs[k] = __sinf(a); xc[k] = __cosf(a);
    }

    // load post-layer-0 state: amps a = pos*8 + r  -> 16 floats at pos*16
    v2f st[8];
    {
        const float4* st4 = (const float4*)g_st0;
        #pragma unroll
        for (int h = 0; h < 4; ++h) {
            float4 v4 = st4[pos * 4 + h];
            st[2*h]   = v2f{ v4.x, v4.y };
            st[2*h+1] = v2f{ v4.z, v4.w };
        }
    }

    // fully unrolled: compile-time table offsets -> hoistable scalar loads
    reup8(st, xc, xs, lane);  ansatz8<false>(st, g_tab + 1*48, lane);
    reup8(st, xc, xs, lane);  ansatz8<false>(st, g_tab + 2*48, lane);
    reup8(st, xc, xs, lane);  ansatz8<false>(st, g_tab + 3*48, lane);
    reup8(st, xc, xs, lane);  ansatz8<true >(st, g_tab + 4*48, lane);  // RZs dropped (exact)

    // per-lane signed partials: reg qubits 5,6,7 <-> r bits 2,1,0
    float p[8];
    #pragma unroll
    for (int r = 0; r < 8; ++r) p[r] = st[r].x*st[r].x + st[r].y*st[r].y;
    float pl = 0.f, z5 = 0.f, z6 = 0.f, z7 = 0.f;
    #pragma unroll
    for (int r = 0; r < 8; ++r) {
        pl += p[r];
        z5 += ((r >> 2) & 1) ? -p[r] : p[r];
        z6 += ((r >> 1) & 1) ? -p[r] : p[r];
        z7 += ( r       & 1) ? -p[r] : p[r];
    }
    float z[8];
    z[0] = pl; z[1] = pl; z[2] = pl; z[3] = pl; z[4] = pl;  // signs in butterfly
    z[5] = z5; z[6] = z6; z[7] = z7;

    bstage8<0>(z, lane); bstage8<1>(z, lane); bstage8<2>(z, lane);
    bstage8<3>(z, lane); bstage8<4>(z, lane);

    // block reduction: 8 circuits -> <=2 batch runs, then few atomics
    __shared__ float zsh[8][NQ];
    __shared__ int bsh[8];
    const int g = tid >> 5;
    if (pos == 0) {
        bsh[g] = b;
        #pragma unroll
        for (int q = 0; q < NQ; ++q) zsh[g][q] = fmaxf(z[q], 0.0f);
    }
    __syncthreads();
    if (tid < 64) {
        const int gg = tid >> 3, q = tid & 7;
        const bool leader = (gg == 0) || (bsh[gg] != bsh[gg - 1]);
        if (leader) {
            float m = zsh[gg][q];
            for (int g2 = gg + 1; g2 < 8 && bsh[g2] == bsh[gg]; ++g2)
                m = fmaxf(m, zsh[g2][q]);
            atomicMax((unsigned int*)(out + bsh[gg] * NQ + q), __float_as_uint(m));
        }
    }
}

extern "C" void kernel_launch(void* const* d_in, const int* in_sizes, int n_in,
                              void* d_out, int out_size, void* d_ws, size_t ws_size,
                              hipStream_t stream) {
    const float* vec = (const float*)d_in[0];   // (8,1,512) float32
    const float* wts = (const float*)d_in[1];   // (5,8,3) float32
    float* out = (float*)d_out;                 // (8,8,1) float32

    hipLaunchKernelGGL(prep_kernel, dim3(1), dim3(256), 0, stream, wts, out);
    const int blocks = NCIRC / 8;               // 511 blocks -> ~2 blocks/CU
    hipLaunchKernelGGL(quanv_kernel, dim3(blocks), dim3(256), 0, stream, vec, out);
}